// Round 4
// baseline (364.638 us; speedup 1.0000x reference)
//
#include <hip/hip_runtime.h>
#include <hip/hip_bf16.h>
#include <hip/hip_cooperative_groups.h>
#include <math.h>

namespace cg = cooperative_groups;

typedef unsigned short u16;
typedef float  f32x4  __attribute__((ext_vector_type(4)));
typedef __bf16 bf16x8 __attribute__((ext_vector_type(8)));

#define NPOS   4000
#define LDP    136       // padded bf16 row stride
#define TILE_CH 2176     // 128*136*2/16 16-byte chunks per 128-row tile
#define MSE_N  4194304

__device__ __forceinline__ void load_lds16(const void* g, void* l) {
  __builtin_amdgcn_global_load_lds(
      (const __attribute__((address_space(1))) unsigned int*)g,
      (__attribute__((address_space(3))) unsigned int*)l, 16, 0, 0);
}

__device__ __forceinline__ float bf2f(u16 h) {
  unsigned u = ((unsigned)h) << 16;
  return __builtin_bit_cast(float, u);
}

struct FusedArgs {
  const float* Zs; const int* pos; const int* neg;
  const float4* fd; const float4* idf;
  u16* Pc; u16* Prow; float* Gpart; u16* Gbf; float* S;
  float* qpos; float* qneg; float* sdpos; float* sdneg;
  float* accs; float* out;
};

__global__ __launch_bounds__(256) void fused_k(FusedArgs a) {
  cg::grid_group grid = cg::this_grid();
  __shared__ __align__(16) u16 T0[128 * LDP];   // 34,816 B
  __shared__ __align__(16) u16 T1[128 * LDP];   // 34,816 B
  __shared__ float Sl[256];
  __shared__ float redf[8];
  int blk = blockIdx.x, tid = threadIdx.x;
  int wave = tid >> 6, lane = tid & 63;

  // ---------------- Phase A: gather+normalize (1 wave/row) + MSE ----------------
  for (int row = blk * 4 + wave; row < 8000; row += 1024) {
    int col = (row < NPOS) ? row : (4096 + row - NPOS);
    int v   = (row < NPOS) ? a.pos[row] : a.neg[row - NPOS];
    const float* zc = a.Zs + v;
    float x0 = zc[(size_t)lane << 15];
    float x1 = zc[(size_t)(lane + 64) << 15];
    float s = x0 * x0 + x1 * x1;
    #pragma unroll
    for (int o = 1; o < 64; o <<= 1) s += __shfl_xor(s, o, 64);
    float inv = 1.0f / fmaxf(sqrtf(s), 1e-12f);
    __hip_bfloat16 h0 = __float2bfloat16(x0 * inv);
    __hip_bfloat16 h1 = __float2bfloat16(x1 * inv);
    u16 b0 = *(u16*)&h0, b1 = *(u16*)&h1;
    a.Prow[(size_t)col * LDP + lane]      = b0;
    a.Prow[(size_t)col * LDP + lane + 64] = b1;
    size_t cbase = (size_t)(col >> 7) * (128 * LDP) + (col & 127);
    a.Pc[cbase + (size_t)lane * LDP]        = b0;
    a.Pc[cbase + (size_t)(lane + 64) * LDP] = b1;
  }
  // zero invalid sample columns (chunk 31 cols 32..127, chunk 63 cols 32..127)
  if (blk >= 254) {
    int ch = (blk == 254) ? 31 : 63;
    for (int e = tid; e < 128 * 96; e += 256) {
      int f = e / 96, c = 32 + e % 96;
      a.Pc[(size_t)ch * (128 * LDP) + (size_t)f * LDP + c] = 0;
    }
  }
  // MSE (grid-stride, fused into phase A)
  {
    float ms = 0.f;
    for (int idx = blk * 256 + tid; idx < MSE_N / 4; idx += 65536) {
      float4 u = a.fd[idx], w = a.idf[idx];
      float dx = u.x - w.x, dy = u.y - w.y, dz = u.z - w.z, dv = u.w - w.w;
      ms += dx * dx + dy * dy + dz * dz + dv * dv;
    }
    #pragma unroll
    for (int o = 1; o < 64; o <<= 1) ms += __shfl_xor(ms, o, 64);
    if (lane == 0) redf[wave] = ms;
    __syncthreads();
    if (tid == 0) atomicAdd(&a.accs[2], redf[0] + redf[1] + redf[2] + redf[3]);
  }
  __threadfence();
  grid.sync();

  // ---------------- Phase B: SYRK (64 blocks, 1 chunk each) + S sums ----------------
  if (blk < 64) {
    const u16* g = a.Pc + (size_t)blk * (128 * LDP);
    #pragma unroll
    for (int k = 0; k < 9; ++k) {
      int cc = k * 256 + tid;
      if (cc < TILE_CH) load_lds16(g + cc * 8, &T0[cc * 8]);
    }
    __syncthreads();
    int wm = (wave >> 1) << 6, wn = (wave & 1) << 6;
    int r = lane & 15, q = lane >> 4;
    f32x4 acc[4][4];
    #pragma unroll
    for (int x = 0; x < 4; ++x)
      #pragma unroll
      for (int y = 0; y < 4; ++y) {
        acc[x][y][0] = 0.f; acc[x][y][1] = 0.f; acc[x][y][2] = 0.f; acc[x][y][3] = 0.f;
      }
    #pragma unroll
    for (int kk = 0; kk < 4; ++kk) {
      int k0 = kk * 32 + q * 8;
      bf16x8 af[4], bfr[4];
      #pragma unroll
      for (int t = 0; t < 4; ++t) {
        af[t]  = *(const bf16x8*)&T0[(wm + t * 16 + r) * LDP + k0];
        bfr[t] = *(const bf16x8*)&T0[(wn + t * 16 + r) * LDP + k0];
      }
      #pragma unroll
      for (int mt = 0; mt < 4; ++mt)
        #pragma unroll
        for (int nt = 0; nt < 4; ++nt)
          acc[mt][nt] = __builtin_amdgcn_mfma_f32_16x16x32_bf16(
              af[mt], bfr[nt], acc[mt][nt], 0, 0, 0);
    }
    float* gp = a.Gpart + (size_t)blk * 16384;
    #pragma unroll
    for (int mt = 0; mt < 4; ++mt)
      #pragma unroll
      for (int nt = 0; nt < 4; ++nt)
        #pragma unroll
        for (int reg = 0; reg < 4; ++reg) {
          int ar = wm + mt * 16 + q * 4 + reg;
          int bc = wn + nt * 16 + r;
          gp[ar * 128 + bc] = acc[mt][nt][reg];
        }
    // S column-sum from staged tile
    int sf = tid >> 1, sh = tid & 1;
    const u16* base = &T0[sf * LDP + sh * 64];
    float ssum = 0.f;
    #pragma unroll
    for (int vb = 0; vb < 8; ++vb) {
      bf16x8 v = *(const bf16x8*)&base[vb * 8];
      #pragma unroll
      for (int j = 0; j < 8; ++j) ssum += (float)v[j];
    }
    ssum += __shfl_xor(ssum, 1, 64);
    if (sh == 0) atomicAdd(&a.S[(blk >> 5) * 128 + sf], ssum);
  }
  __threadfence();
  grid.sync();

  // ---------------- Phase C: reduce Gpart -> Gbf ----------------
  if (blk < 128) {
    int idx = blk * 256 + tid;
    int set = idx >> 14, e = idx & 16383;
    float sum = 0.f;
    #pragma unroll
    for (int p = 0; p < 32; ++p)
      sum += a.Gpart[(size_t)(set * 32 + p) * 16384 + e];
    __hip_bfloat16 h = __float2bfloat16(sum);
    a.Gbf[(size_t)set * (128 * LDP) + (size_t)(e >> 7) * LDP + (e & 127)] = *(u16*)&h;
  }
  __threadfence();
  grid.sync();

  // ---------------- Phase D: quadratic forms + S-dots ----------------
  if (blk < 128) {
    int cb = blk & 63, set = blk >> 6;
    Sl[tid] = a.S[tid];
    const u16* gG = a.Gbf + (size_t)set * (128 * LDP);
    const u16* gP = a.Prow + (size_t)cb * (128 * LDP);
    #pragma unroll
    for (int k = 0; k < 9; ++k) {
      int cc = k * 256 + tid;
      if (cc < TILE_CH) {
        load_lds16(gG + cc * 8, &T0[cc * 8]);
        load_lds16(gP + cc * 8, &T1[cc * 8]);
      }
    }
    __syncthreads();
    int wm = (wave >> 1) << 6, wn = (wave & 1) << 6;
    int r = lane & 15, q = lane >> 4;
    f32x4 acc[4][4];
    #pragma unroll
    for (int x = 0; x < 4; ++x)
      #pragma unroll
      for (int y = 0; y < 4; ++y) {
        acc[x][y][0] = 0.f; acc[x][y][1] = 0.f; acc[x][y][2] = 0.f; acc[x][y][3] = 0.f;
      }
    #pragma unroll
    for (int kk = 0; kk < 4; ++kk) {
      int k0 = kk * 32 + q * 8;
      bf16x8 af[4], bfr[4];
      #pragma unroll
      for (int t = 0; t < 4; ++t) {
        af[t]  = *(const bf16x8*)&T0[(wm + t * 16 + r) * LDP + k0];
        bfr[t] = *(const bf16x8*)&T1[(wn + t * 16 + r) * LDP + k0];
      }
      #pragma unroll
      for (int mt = 0; mt < 4; ++mt)
        #pragma unroll
        for (int nt = 0; nt < 4; ++nt)
          acc[mt][nt] = __builtin_amdgcn_mfma_f32_16x16x32_bf16(
              af[mt], bfr[nt], acc[mt][nt], 0, 0, 0);
    }
    // q epilogue: Y[a][i] dotted with P[i][a], reduced over a
    float qv[4] = {0.f, 0.f, 0.f, 0.f};
    #pragma unroll
    for (int nt = 0; nt < 4; ++nt) {
      int il = wn + nt * 16 + r;
      #pragma unroll
      for (int mt = 0; mt < 4; ++mt) {
        const u16* pp = &T1[il * LDP + wm + mt * 16 + q * 4];
        #pragma unroll
        for (int reg = 0; reg < 4; ++reg)
          qv[nt] += acc[mt][nt][reg] * bf2f(pp[reg]);
      }
    }
    #pragma unroll
    for (int nt = 0; nt < 4; ++nt) {
      qv[nt] += __shfl_xor(qv[nt], 16, 64);
      qv[nt] += __shfl_xor(qv[nt], 32, 64);
    }
    float* qarr = set ? a.qneg : a.qpos;
    if (q == 0) {
      #pragma unroll
      for (int nt = 0; nt < 4; ++nt)
        atomicAdd(&qarr[cb * 128 + wn + nt * 16 + r], qv[nt]);
    }
    // S-dots (only set==0 blocks)
    if (set == 0) {
      int which = tid >> 7, sl = tid & 127;
      const float* Sv = &Sl[which * 128];
      float d = 0.f;
      #pragma unroll
      for (int fb = 0; fb < 16; ++fb) {
        const u16* pv = &T1[sl * LDP + fb * 8];
        #pragma unroll
        for (int j = 0; j < 8; ++j) d += Sv[fb * 8 + j] * bf2f(pv[j]);
      }
      (which ? a.sdneg : a.sdpos)[cb * 128 + sl] = d;
    }
  }
  __threadfence();
  grid.sync();

  // ---------------- Phase E: per-sample terms + final combine ----------------
  if (blk == 0) {
    float lg = 0.f, sm = 0.f;
    for (int col = tid; col < 8192; col += 256) {
      bool isp = col < NPOS;
      bool isn = (col >= 4096) && (col < 8096);
      if (isp || isn) {
        float qp = a.qpos[col], qn = a.qneg[col];
        float c = 1.0f / sqrtf(qp + qn);
        float qo  = isp ? qn : qp;
        float sdo = isp ? a.sdneg[col] : a.sdpos[col];
        float sds = isp ? a.sdpos[col] : a.sdneg[col];
        float denom = 4000.0f + c * sdo + 0.5f * c * c * qo;
        lg += logf(denom);
        sm += c * (sds - 1.0f);
      }
    }
    #pragma unroll
    for (int o = 1; o < 64; o <<= 1) {
      lg += __shfl_xor(lg, o, 64);
      sm += __shfl_xor(sm, o, 64);
    }
    if (lane == 0) { redf[wave] = lg; redf[4 + wave] = sm; }
    __syncthreads();
    if (tid == 0) {
      float lgs = redf[0] + redf[1] + redf[2] + redf[3];
      float sms = redf[4] + redf[5] + redf[6] + redf[7];
      a.out[0] = lgs - sms * (1.0f / 8000.0f)
               + 0.5f * (a.accs[2] * (1.0f / (float)MSE_N));
    }
  }
}

extern "C" void kernel_launch(void* const* d_in, const int* in_sizes, int n_in,
                              void* d_out, int out_size, void* d_ws, size_t ws_size,
                              hipStream_t stream) {
  char* ws = (char*)d_ws;
  FusedArgs args;
  args.Zs  = (const float*)d_in[0];
  args.pos = (const int*)d_in[1];
  args.neg = (const int*)d_in[2];
  args.fd  = (const float4*)d_in[3];
  args.idf = (const float4*)d_in[4];
  args.out = (float*)d_out;

  args.Pc    = (u16*)(ws + 0);            // 2,228,224 B
  args.Prow  = (u16*)(ws + 2228224);      // 2,228,224 B -> 4,456,448
  args.Gbf   = (u16*)(ws + 4456448);      //    69,632 B -> 4,526,080
  args.Gpart = (float*)(ws + 4526080);    // 4,194,304 B -> 8,720,384
  args.sdpos = (float*)(ws + 8720384);    //    32,768 B -> 8,753,152
  args.sdneg = (float*)(ws + 8753152);    //    32,768 B -> 8,785,920
  args.qpos  = (float*)(ws + 8785920);    //    32,768 B -> 8,818,688  (zeroed)
  args.qneg  = (float*)(ws + 8818688);    //    32,768 B -> 8,851,456  (zeroed)
  args.S     = (float*)(ws + 8851456);    //     1,024 B -> 8,852,480  (zeroed)
  args.accs  = (float*)(ws + 8852480);    //        16 B -> 8,852,496  (zeroed)

  // zero only the atomic-accumulated region (qpos..accs)
  hipMemsetAsync(ws + 8785920, 0, 66576, stream);

  void* kargs[] = { &args };
  hipLaunchCooperativeKernel((void*)fused_k, dim3(256), dim3(256), kargs, 0, stream);
}

// Round 5
// 232.633 us; speedup vs baseline: 1.5674x; 1.5674x over previous
//
#include <hip/hip_runtime.h>
#include <hip/hip_bf16.h>
#include <hip/hip_cooperative_groups.h>
#include <math.h>

namespace cg = cooperative_groups;

typedef unsigned short u16;
typedef float  f32x4  __attribute__((ext_vector_type(4)));
typedef __bf16 bf16x8 __attribute__((ext_vector_type(8)));

#define NPOS   4000
#define LDP    136       // padded bf16 row stride
#define TILE_CH 2176     // 128*136*2/16 16-byte chunks per 128-row tile
#define MSE_N  4194304
#define GATHER_B 2000
#define MSE_B    512

__device__ __forceinline__ void load_lds16(const void* g, void* l) {
  __builtin_amdgcn_global_load_lds(
      (const __attribute__((address_space(1))) unsigned int*)g,
      (__attribute__((address_space(3))) unsigned int*)l, 16, 0, 0);
}

__device__ __forceinline__ float bf2f(u16 h) {
  unsigned u = ((unsigned)h) << 16;
  return __builtin_bit_cast(float, u);
}

struct Args {
  const float* Zs; const int* pos; const int* neg;
  const float4* fd; const float4* idf;
  u16* Pc; u16* Prow; float* Gpart; u16* Gbf;
  float* Spart; float* S;
  float* qpos; float* qneg; float* sdpos; float* sdneg;
  float* msepart; float* out;
};

// ============ kernel 1: gather+normalize (high TLP) + MSE partials + pad zero ======
__global__ __launch_bounds__(256) void prep_k(Args a) {
  int blk = blockIdx.x, tid = threadIdx.x;
  int wave = tid >> 6, lane = tid & 63;
  if (blk < GATHER_B) {
    int row = blk * 4 + wave;                 // 0..7999, one wave per row
    int col = (row < NPOS) ? row : (4096 + row - NPOS);
    int v   = (row < NPOS) ? a.pos[row] : a.neg[row - NPOS];
    const float* zc = a.Zs + v;
    float x0 = zc[(size_t)lane << 15];
    float x1 = zc[(size_t)(lane + 64) << 15];
    float s = x0 * x0 + x1 * x1;
    #pragma unroll
    for (int o = 1; o < 64; o <<= 1) s += __shfl_xor(s, o, 64);
    float inv = 1.0f / fmaxf(sqrtf(s), 1e-12f);
    __hip_bfloat16 h0 = __float2bfloat16(x0 * inv);
    __hip_bfloat16 h1 = __float2bfloat16(x1 * inv);
    u16 b0 = *(u16*)&h0, b1 = *(u16*)&h1;
    a.Prow[(size_t)col * LDP + lane]      = b0;
    a.Prow[(size_t)col * LDP + lane + 64] = b1;
    size_t cbase = (size_t)(col >> 7) * (128 * LDP) + (col & 127);
    a.Pc[cbase + (size_t)lane * LDP]        = b0;
    a.Pc[cbase + (size_t)(lane + 64) * LDP] = b1;
  } else if (blk < GATHER_B + MSE_B) {
    int b = blk - GATHER_B;
    float ms = 0.f;
    for (int idx = b * 256 + tid; idx < MSE_N / 4; idx += MSE_B * 256) {
      float4 u = a.fd[idx], w = a.idf[idx];
      float dx = u.x - w.x, dy = u.y - w.y, dz = u.z - w.z, dv = u.w - w.w;
      ms += dx * dx + dy * dy + dz * dz + dv * dv;
    }
    #pragma unroll
    for (int o = 1; o < 64; o <<= 1) ms += __shfl_xor(ms, o, 64);
    __shared__ float red[4];
    if (lane == 0) red[wave] = ms;
    __syncthreads();
    if (tid == 0) a.msepart[b] = red[0] + red[1] + red[2] + red[3];
  } else {
    // zero invalid Pc sample columns (chunk 31 & 63, cols 32..127)
    int ch = (blk == GATHER_B + MSE_B) ? 31 : 63;
    for (int e = tid; e < 128 * 96; e += 256) {
      int f = e / 96, c = 32 + e % 96;
      a.Pc[(size_t)ch * (128 * LDP) + (size_t)f * LDP + c] = 0;
    }
  }
}

// ============ kernel 2: cooperative SYRK -> reduce -> quad -> final ============
__global__ __launch_bounds__(256) void solve_k(Args a) {
  cg::grid_group grid = cg::this_grid();
  __shared__ __align__(16) u16 T0[128 * LDP];
  __shared__ __align__(16) u16 T1[128 * LDP];
  __shared__ float Sl[256];
  __shared__ float qld[2][128];
  __shared__ float redf[8];
  int blk = blockIdx.x, tid = threadIdx.x;
  int wave = tid >> 6, lane = tid & 63;
  int wm = (wave >> 1) << 6, wn = (wave & 1) << 6;
  int r = lane & 15, q = lane >> 4;

  // ---- Phase B: SYRK partials (64 blocks, 1 chunk each) + S chunk-sums ----
  if (blk < 64) {
    const u16* g = a.Pc + (size_t)blk * (128 * LDP);
    #pragma unroll
    for (int k = 0; k < 9; ++k) {
      int cc = k * 256 + tid;
      if (cc < TILE_CH) load_lds16(g + cc * 8, &T0[cc * 8]);
    }
    __syncthreads();
    f32x4 acc[4][4];
    #pragma unroll
    for (int x = 0; x < 4; ++x)
      #pragma unroll
      for (int y = 0; y < 4; ++y) {
        acc[x][y][0] = 0.f; acc[x][y][1] = 0.f; acc[x][y][2] = 0.f; acc[x][y][3] = 0.f;
      }
    #pragma unroll
    for (int kk = 0; kk < 4; ++kk) {
      int k0 = kk * 32 + q * 8;
      bf16x8 af[4], bfr[4];
      #pragma unroll
      for (int t = 0; t < 4; ++t) {
        af[t]  = *(const bf16x8*)&T0[(wm + t * 16 + r) * LDP + k0];
        bfr[t] = *(const bf16x8*)&T0[(wn + t * 16 + r) * LDP + k0];
      }
      #pragma unroll
      for (int mt = 0; mt < 4; ++mt)
        #pragma unroll
        for (int nt = 0; nt < 4; ++nt)
          acc[mt][nt] = __builtin_amdgcn_mfma_f32_16x16x32_bf16(
              af[mt], bfr[nt], acc[mt][nt], 0, 0, 0);
    }
    float* gp = a.Gpart + (size_t)blk * 16384;
    #pragma unroll
    for (int mt = 0; mt < 4; ++mt)
      #pragma unroll
      for (int nt = 0; nt < 4; ++nt)
        #pragma unroll
        for (int reg = 0; reg < 4; ++reg) {
          int ar = wm + mt * 16 + q * 4 + reg;
          int bc = wn + nt * 16 + r;
          gp[ar * 128 + bc] = acc[mt][nt][reg];
        }
    // S chunk-sum from staged tile (non-atomic partials)
    int sf = tid >> 1, sh = tid & 1;
    const u16* base = &T0[sf * LDP + sh * 64];
    float ssum = 0.f;
    #pragma unroll
    for (int vb = 0; vb < 8; ++vb) {
      bf16x8 v = *(const bf16x8*)&base[vb * 8];
      #pragma unroll
      for (int j = 0; j < 8; ++j) ssum += (float)v[j];
    }
    ssum += __shfl_xor(ssum, 1, 64);
    if (sh == 0) a.Spart[blk * 128 + sf] = ssum;
  }
  __threadfence();
  grid.sync();

  // ---- Phase C: reduce Gpart -> Gbf (128 blocks); block 0 also reduces S ----
  if (blk < 128) {
    int idx = blk * 256 + tid;
    int set = idx >> 14, e = idx & 16383;
    float sum = 0.f;
    #pragma unroll
    for (int p = 0; p < 32; ++p)
      sum += a.Gpart[(size_t)(set * 32 + p) * 16384 + e];
    __hip_bfloat16 h = __float2bfloat16(sum);
    a.Gbf[(size_t)set * (128 * LDP) + (size_t)(e >> 7) * LDP + (e & 127)] = *(u16*)&h;
  }
  if (blk == 0) {
    int set = tid >> 7, f = tid & 127;
    float s = 0.f;
    #pragma unroll
    for (int c = 0; c < 32; ++c) s += a.Spart[(set * 32 + c) * 128 + f];
    a.S[tid] = s;
  }
  __threadfence();
  grid.sync();

  // ---- Phase D: quadratic forms + S-dots (128 blocks) ----
  if (blk < 128) {
    int cb = blk & 63, set = blk >> 6;
    Sl[tid] = a.S[tid];
    const u16* gG = a.Gbf + (size_t)set * (128 * LDP);
    const u16* gP = a.Prow + (size_t)cb * (128 * LDP);
    #pragma unroll
    for (int k = 0; k < 9; ++k) {
      int cc = k * 256 + tid;
      if (cc < TILE_CH) {
        load_lds16(gG + cc * 8, &T0[cc * 8]);
        load_lds16(gP + cc * 8, &T1[cc * 8]);
      }
    }
    __syncthreads();
    f32x4 acc[4][4];
    #pragma unroll
    for (int x = 0; x < 4; ++x)
      #pragma unroll
      for (int y = 0; y < 4; ++y) {
        acc[x][y][0] = 0.f; acc[x][y][1] = 0.f; acc[x][y][2] = 0.f; acc[x][y][3] = 0.f;
      }
    #pragma unroll
    for (int kk = 0; kk < 4; ++kk) {
      int k0 = kk * 32 + q * 8;
      bf16x8 af[4], bfr[4];
      #pragma unroll
      for (int t = 0; t < 4; ++t) {
        af[t]  = *(const bf16x8*)&T0[(wm + t * 16 + r) * LDP + k0];
        bfr[t] = *(const bf16x8*)&T1[(wn + t * 16 + r) * LDP + k0];
      }
      #pragma unroll
      for (int mt = 0; mt < 4; ++mt)
        #pragma unroll
        for (int nt = 0; nt < 4; ++nt)
          acc[mt][nt] = __builtin_amdgcn_mfma_f32_16x16x32_bf16(
              af[mt], bfr[nt], acc[mt][nt], 0, 0, 0);
    }
    // q epilogue: Y[a][i] dotted with P[i][a], reduced over a
    float qv[4] = {0.f, 0.f, 0.f, 0.f};
    #pragma unroll
    for (int nt = 0; nt < 4; ++nt) {
      int il = wn + nt * 16 + r;
      #pragma unroll
      for (int mt = 0; mt < 4; ++mt) {
        const u16* pp = &T1[il * LDP + wm + mt * 16 + q * 4];
        #pragma unroll
        for (int reg = 0; reg < 4; ++reg)
          qv[nt] += acc[mt][nt][reg] * bf2f(pp[reg]);
      }
    }
    #pragma unroll
    for (int nt = 0; nt < 4; ++nt) {
      qv[nt] += __shfl_xor(qv[nt], 16, 64);
      qv[nt] += __shfl_xor(qv[nt], 32, 64);
    }
    // combine the two wave-halves (wm=0 / wm=64) through LDS, store non-atomic
    int half = wm >> 6;
    if (q == 0) {
      #pragma unroll
      for (int nt = 0; nt < 4; ++nt) qld[half][wn + nt * 16 + r] = qv[nt];
    }
    __syncthreads();
    float* qarr = set ? a.qneg : a.qpos;
    if (tid < 128) qarr[cb * 128 + tid] = qld[0][tid] + qld[1][tid];
    // S-dots (only set==0 blocks)
    if (set == 0) {
      int which = tid >> 7, sl = tid & 127;
      const float* Sv = &Sl[which * 128];
      float d = 0.f;
      #pragma unroll
      for (int fb = 0; fb < 16; ++fb) {
        const u16* pv = &T1[sl * LDP + fb * 8];
        #pragma unroll
        for (int j = 0; j < 8; ++j) d += Sv[fb * 8 + j] * bf2f(pv[j]);
      }
      (which ? a.sdneg : a.sdpos)[cb * 128 + sl] = d;
    }
  }
  __threadfence();
  grid.sync();

  // ---- Phase E: per-sample terms + MSE partial reduce + final combine ----
  if (blk == 0) {
    float lg = 0.f, sm = 0.f;
    for (int col = tid; col < 8192; col += 256) {
      bool isp = col < NPOS;
      bool isn = (col >= 4096) && (col < 4096 + NPOS);
      if (isp || isn) {
        float qp = a.qpos[col], qn = a.qneg[col];
        float c = 1.0f / sqrtf(qp + qn);
        float qo  = isp ? qn : qp;
        float sdo = isp ? a.sdneg[col] : a.sdpos[col];
        float sds = isp ? a.sdpos[col] : a.sdneg[col];
        float denom = 4000.0f + c * sdo + 0.5f * c * c * qo;
        lg += logf(denom);
        sm += c * (sds - 1.0f);
      }
    }
    float ms = a.msepart[tid] + a.msepart[tid + 256];
    #pragma unroll
    for (int o = 1; o < 64; o <<= 1) {
      lg += __shfl_xor(lg, o, 64);
      sm += __shfl_xor(sm, o, 64);
      ms += __shfl_xor(ms, o, 64);
    }
    if (lane == 0) { redf[wave] = lg; redf[4 + wave] = sm; Sl[wave] = ms; }
    __syncthreads();
    if (tid == 0) {
      float lgs = redf[0] + redf[1] + redf[2] + redf[3];
      float sms = redf[4] + redf[5] + redf[6] + redf[7];
      float mss = Sl[0] + Sl[1] + Sl[2] + Sl[3];
      a.out[0] = lgs - sms * (1.0f / 8000.0f) + 0.5f * (mss * (1.0f / (float)MSE_N));
    }
  }
}

extern "C" void kernel_launch(void* const* d_in, const int* in_sizes, int n_in,
                              void* d_out, int out_size, void* d_ws, size_t ws_size,
                              hipStream_t stream) {
  char* ws = (char*)d_ws;
  Args args;
  args.Zs  = (const float*)d_in[0];
  args.pos = (const int*)d_in[1];
  args.neg = (const int*)d_in[2];
  args.fd  = (const float4*)d_in[3];
  args.idf = (const float4*)d_in[4];
  args.out = (float*)d_out;

  args.Pc      = (u16*)(ws + 0);            // 2,228,224 B
  args.Prow    = (u16*)(ws + 2228224);      // 2,228,224 -> 4,456,448
  args.Gbf     = (u16*)(ws + 4456448);      //    69,632 -> 4,526,080
  args.Gpart   = (float*)(ws + 4526080);    // 4,194,304 -> 8,720,384
  args.Spart   = (float*)(ws + 8720384);    //    32,768 -> 8,753,152
  args.S       = (float*)(ws + 8753152);    //     1,024 -> 8,754,176
  args.sdpos   = (float*)(ws + 8754176);    //    32,768 -> 8,786,944
  args.sdneg   = (float*)(ws + 8786944);    //    32,768 -> 8,819,712
  args.qpos    = (float*)(ws + 8819712);    //    32,768 -> 8,852,480
  args.qneg    = (float*)(ws + 8852480);    //    32,768 -> 8,885,248
  args.msepart = (float*)(ws + 8885248);    //     2,048 -> 8,887,296

  prep_k<<<GATHER_B + MSE_B + 2, 256, 0, stream>>>(args);
  void* kargs[] = { &args };
  hipLaunchCooperativeKernel((void*)solve_k, dim3(128), dim3(256), kargs, 0, stream);
}

// Round 6
// 139.381 us; speedup vs baseline: 2.6161x; 1.6690x over previous
//
#include <hip/hip_runtime.h>
#include <hip/hip_bf16.h>
#include <math.h>

typedef unsigned short u16;
typedef float  f32x4  __attribute__((ext_vector_type(4)));
typedef __bf16 bf16x8 __attribute__((ext_vector_type(8)));

#define NPOS   4000
#define LDP    136       // padded bf16 row stride
#define TILE_CH 2176     // 128*136*2/16 16-byte chunks per 128-row tile
#define MSE_N  4194304
#define GATHER_B 2000
#define MSE_B    512

__device__ __forceinline__ void load_lds16(const void* g, void* l) {
  __builtin_amdgcn_global_load_lds(
      (const __attribute__((address_space(1))) unsigned int*)g,
      (__attribute__((address_space(3))) unsigned int*)l, 16, 0, 0);
}

__device__ __forceinline__ float bf2f(u16 h) {
  unsigned u = ((unsigned)h) << 16;
  return __builtin_bit_cast(float, u);
}

struct Args {
  const float* Zs; const int* pos; const int* neg;
  const float4* fd; const float4* idf;
  u16* Pc; u16* Prow; float* G; float* S;
  float* qpos; float* qneg; float* sdpos; float* sdneg;
  float* msepart; float* out;
};

// ===== kernel 1: gather+normalize (high TLP) + MSE partials + Pc pad zero =====
__global__ __launch_bounds__(256) void prep_k(Args a) {
  int blk = blockIdx.x, tid = threadIdx.x;
  int wave = tid >> 6, lane = tid & 63;
  if (blk < GATHER_B) {
    int row = blk * 4 + wave;                 // one wave per row
    int col = (row < NPOS) ? row : (4096 + row - NPOS);
    int v   = (row < NPOS) ? a.pos[row] : a.neg[row - NPOS];
    const float* zc = a.Zs + v;
    float x0 = zc[(size_t)lane << 15];
    float x1 = zc[(size_t)(lane + 64) << 15];
    float s = x0 * x0 + x1 * x1;
    #pragma unroll
    for (int o = 1; o < 64; o <<= 1) s += __shfl_xor(s, o, 64);
    float inv = 1.0f / fmaxf(sqrtf(s), 1e-12f);
    __hip_bfloat16 h0 = __float2bfloat16(x0 * inv);
    __hip_bfloat16 h1 = __float2bfloat16(x1 * inv);
    u16 b0 = *(u16*)&h0, b1 = *(u16*)&h1;
    a.Prow[(size_t)col * LDP + lane]      = b0;
    a.Prow[(size_t)col * LDP + lane + 64] = b1;
    size_t cbase = (size_t)(col >> 7) * (128 * LDP) + (col & 127);
    a.Pc[cbase + (size_t)lane * LDP]        = b0;
    a.Pc[cbase + (size_t)(lane + 64) * LDP] = b1;
  } else if (blk < GATHER_B + MSE_B) {
    int b = blk - GATHER_B;
    float ms = 0.f;
    for (int idx = b * 256 + tid; idx < MSE_N / 4; idx += MSE_B * 256) {
      float4 u = a.fd[idx], w = a.idf[idx];
      float dx = u.x - w.x, dy = u.y - w.y, dz = u.z - w.z, dv = u.w - w.w;
      ms += dx * dx + dy * dy + dz * dz + dv * dv;
    }
    #pragma unroll
    for (int o = 1; o < 64; o <<= 1) ms += __shfl_xor(ms, o, 64);
    __shared__ float red[4];
    if (lane == 0) red[wave] = ms;
    __syncthreads();
    if (tid == 0) a.msepart[b] = red[0] + red[1] + red[2] + red[3];
  } else {
    // zero invalid Pc sample columns (chunk 31 & 63, cols 32..127)
    int ch = (blk == GATHER_B + MSE_B) ? 31 : 63;
    for (int e = tid; e < 128 * 96; e += 256) {
      int f = e / 96, c = 32 + e % 96;
      a.Pc[(size_t)ch * (128 * LDP) + (size_t)f * LDP + c] = 0;
    }
  }
}

// ===== kernel 2: SYRK -> atomic G[2][128][128] f32, + S column-sum atomics =====
__global__ __launch_bounds__(256) void syrk_k(Args a) {
  __shared__ __align__(16) u16 T0[128 * LDP];
  int blk = blockIdx.x, tid = threadIdx.x;     // 16 blocks: b<8 pos, b>=8 neg
  int wave = tid >> 6, lane = tid & 63;
  int wm = (wave >> 1) << 6, wn = (wave & 1) << 6;
  int r = lane & 15, q = lane >> 4;
  int sf = tid >> 1, sh = tid & 1;
  float ssum = 0.f;
  f32x4 acc[4][4];
  #pragma unroll
  for (int x = 0; x < 4; ++x)
    #pragma unroll
    for (int y = 0; y < 4; ++y) {
      acc[x][y][0] = 0.f; acc[x][y][1] = 0.f; acc[x][y][2] = 0.f; acc[x][y][3] = 0.f;
    }
  for (int it = 0; it < 4; ++it) {
    const u16* g = a.Pc + (size_t)(blk * 4 + it) * (128 * LDP);
    #pragma unroll
    for (int k = 0; k < 9; ++k) {
      int cc = k * 256 + tid;
      if (cc < TILE_CH) load_lds16(g + cc * 8, &T0[cc * 8]);
    }
    __syncthreads();
    #pragma unroll
    for (int kk = 0; kk < 4; ++kk) {
      int k0 = kk * 32 + q * 8;
      bf16x8 af[4], bfr[4];
      #pragma unroll
      for (int t = 0; t < 4; ++t) {
        af[t]  = *(const bf16x8*)&T0[(wm + t * 16 + r) * LDP + k0];
        bfr[t] = *(const bf16x8*)&T0[(wn + t * 16 + r) * LDP + k0];
      }
      #pragma unroll
      for (int mt = 0; mt < 4; ++mt)
        #pragma unroll
        for (int nt = 0; nt < 4; ++nt)
          acc[mt][nt] = __builtin_amdgcn_mfma_f32_16x16x32_bf16(
              af[mt], bfr[nt], acc[mt][nt], 0, 0, 0);
    }
    // S column-sum partial from staged tile
    {
      const u16* base = &T0[sf * LDP + sh * 64];
      #pragma unroll
      for (int vb = 0; vb < 8; ++vb) {
        bf16x8 v = *(const bf16x8*)&base[vb * 8];
        #pragma unroll
        for (int j = 0; j < 8; ++j) ssum += (float)v[j];
      }
    }
    __syncthreads();
  }
  float* Gf = a.G + (size_t)(blk >> 3) * 16384;
  #pragma unroll
  for (int mt = 0; mt < 4; ++mt)
    #pragma unroll
    for (int nt = 0; nt < 4; ++nt)
      #pragma unroll
      for (int reg = 0; reg < 4; ++reg) {
        int ar = wm + mt * 16 + q * 4 + reg;
        int bc = wn + nt * 16 + r;
        atomicAdd(&Gf[ar * 128 + bc], acc[mt][nt][reg]);
      }
  ssum += __shfl_xor(ssum, 1, 64);
  if (sh == 0) atomicAdd(&a.S[(blk >> 3) * 128 + sf], ssum);
}

// ===== kernel 3: quadratic forms q_set[i] = p_i^T G_set p_i + S-dots =====
__global__ __launch_bounds__(256) void quad_k(Args a) {
  __shared__ __align__(16) u16 T0[128 * LDP];   // G in bf16
  __shared__ __align__(16) u16 T1[128 * LDP];   // P tile
  __shared__ float Sl[256];
  __shared__ float qld[2][128];
  int cb = blockIdx.x & 63, set = blockIdx.x >> 6, tid = threadIdx.x;
  Sl[tid] = a.S[tid];
  // stage P tile
  const u16* gP = a.Prow + (size_t)cb * (128 * LDP);
  #pragma unroll
  for (int k = 0; k < 9; ++k) {
    int cc = k * 256 + tid;
    if (cc < TILE_CH) load_lds16(gP + cc * 8, &T1[cc * 8]);
  }
  // load G (f32, L2-hot) and convert to bf16 in LDS
  {
    int f = tid >> 1, half = (tid & 1) * 64;
    const float4* gsrc = (const float4*)(a.G + (size_t)set * 16384 + f * 128 + half);
    #pragma unroll
    for (int j16 = 0; j16 < 16; ++j16) {
      float4 v = gsrc[j16];
      __hip_bfloat16 c0 = __float2bfloat16(v.x), c1 = __float2bfloat16(v.y);
      __hip_bfloat16 c2 = __float2bfloat16(v.z), c3 = __float2bfloat16(v.w);
      ushort4 pk = { *(u16*)&c0, *(u16*)&c1, *(u16*)&c2, *(u16*)&c3 };
      *(ushort4*)&T0[f * LDP + half + j16 * 4] = pk;
    }
  }
  __syncthreads();
  int wave = tid >> 6, lane = tid & 63;
  int wm = (wave >> 1) << 6, wn = (wave & 1) << 6;
  int r = lane & 15, q = lane >> 4;
  f32x4 acc[4][4];
  #pragma unroll
  for (int x = 0; x < 4; ++x)
    #pragma unroll
    for (int y = 0; y < 4; ++y) {
      acc[x][y][0] = 0.f; acc[x][y][1] = 0.f; acc[x][y][2] = 0.f; acc[x][y][3] = 0.f;
    }
  #pragma unroll
  for (int kk = 0; kk < 4; ++kk) {
    int k0 = kk * 32 + q * 8;
    bf16x8 af[4], bfr[4];
    #pragma unroll
    for (int t = 0; t < 4; ++t) {
      af[t]  = *(const bf16x8*)&T0[(wm + t * 16 + r) * LDP + k0];
      bfr[t] = *(const bf16x8*)&T1[(wn + t * 16 + r) * LDP + k0];
    }
    #pragma unroll
    for (int mt = 0; mt < 4; ++mt)
      #pragma unroll
      for (int nt = 0; nt < 4; ++nt)
        acc[mt][nt] = __builtin_amdgcn_mfma_f32_16x16x32_bf16(
            af[mt], bfr[nt], acc[mt][nt], 0, 0, 0);
  }
  // q epilogue: Y[a][i] dotted with P[i][a], reduced over a
  float qv[4] = {0.f, 0.f, 0.f, 0.f};
  #pragma unroll
  for (int nt = 0; nt < 4; ++nt) {
    int il = wn + nt * 16 + r;
    #pragma unroll
    for (int mt = 0; mt < 4; ++mt) {
      const u16* pp = &T1[il * LDP + wm + mt * 16 + q * 4];
      #pragma unroll
      for (int reg = 0; reg < 4; ++reg)
        qv[nt] += acc[mt][nt][reg] * bf2f(pp[reg]);
    }
  }
  #pragma unroll
  for (int nt = 0; nt < 4; ++nt) {
    qv[nt] += __shfl_xor(qv[nt], 16, 64);
    qv[nt] += __shfl_xor(qv[nt], 32, 64);
  }
  int half = wm >> 6;
  if (q == 0) {
    #pragma unroll
    for (int nt = 0; nt < 4; ++nt) qld[half][wn + nt * 16 + r] = qv[nt];
  }
  __syncthreads();
  float* qarr = set ? a.qneg : a.qpos;
  if (tid < 128) qarr[cb * 128 + tid] = qld[0][tid] + qld[1][tid];
  // S-dots (only set==0 blocks)
  if (set == 0) {
    int which = tid >> 7, sl = tid & 127;
    const float* Sv = &Sl[which * 128];
    float d = 0.f;
    #pragma unroll
    for (int fb = 0; fb < 16; ++fb) {
      const u16* pv = &T1[sl * LDP + fb * 8];
      #pragma unroll
      for (int j = 0; j < 8; ++j) d += Sv[fb * 8 + j] * bf2f(pv[j]);
    }
    (which ? a.sdneg : a.sdpos)[cb * 128 + sl] = d;
  }
}

// ===== kernel 4: per-sample terms + MSE reduce + final combine =====
__global__ __launch_bounds__(256) void final_k(Args a) {
  int tid = threadIdx.x;
  int wave = tid >> 6, lane = tid & 63;
  float lg = 0.f, sm = 0.f;
  for (int col = tid; col < 8192; col += 256) {
    bool isp = col < NPOS;
    bool isn = (col >= 4096) && (col < 4096 + NPOS);
    if (isp || isn) {
      float qp = a.qpos[col], qn = a.qneg[col];
      float c = 1.0f / sqrtf(qp + qn);
      float qo  = isp ? qn : qp;
      float sdo = isp ? a.sdneg[col] : a.sdpos[col];
      float sds = isp ? a.sdpos[col] : a.sdneg[col];
      float denom = 4000.0f + c * sdo + 0.5f * c * c * qo;
      lg += logf(denom);
      sm += c * (sds - 1.0f);
    }
  }
  float ms = a.msepart[tid] + a.msepart[tid + 256];
  #pragma unroll
  for (int o = 1; o < 64; o <<= 1) {
    lg += __shfl_xor(lg, o, 64);
    sm += __shfl_xor(sm, o, 64);
    ms += __shfl_xor(ms, o, 64);
  }
  __shared__ float redf[12];
  if (lane == 0) { redf[wave] = lg; redf[4 + wave] = sm; redf[8 + wave] = ms; }
  __syncthreads();
  if (tid == 0) {
    float lgs = redf[0] + redf[1] + redf[2] + redf[3];
    float sms = redf[4] + redf[5] + redf[6] + redf[7];
    float mss = redf[8] + redf[9] + redf[10] + redf[11];
    a.out[0] = lgs - sms * (1.0f / 8000.0f) + 0.5f * (mss * (1.0f / (float)MSE_N));
  }
}

extern "C" void kernel_launch(void* const* d_in, const int* in_sizes, int n_in,
                              void* d_out, int out_size, void* d_ws, size_t ws_size,
                              hipStream_t stream) {
  char* ws = (char*)d_ws;
  Args args;
  args.Zs  = (const float*)d_in[0];
  args.pos = (const int*)d_in[1];
  args.neg = (const int*)d_in[2];
  args.fd  = (const float4*)d_in[3];
  args.idf = (const float4*)d_in[4];
  args.out = (float*)d_out;

  args.Pc      = (u16*)(ws + 0);            // 2,228,224 B
  args.Prow    = (u16*)(ws + 2228224);      // 2,228,224 -> 4,456,448
  args.G       = (float*)(ws + 4456448);    //   131,072 -> 4,587,520 (zeroed)
  args.S       = (float*)(ws + 4587520);    //     1,024 -> 4,588,544 (zeroed)
  args.qpos    = (float*)(ws + 4588544);    //    32,768 -> 4,621,312
  args.qneg    = (float*)(ws + 4621312);    //    32,768 -> 4,654,080
  args.sdpos   = (float*)(ws + 4654080);    //    32,768 -> 4,686,848
  args.sdneg   = (float*)(ws + 4686848);    //    32,768 -> 4,719,616
  args.msepart = (float*)(ws + 4719616);    //     2,048 -> 4,721,664

  hipMemsetAsync(ws + 4456448, 0, 132096, stream);   // G + S only
  prep_k<<<GATHER_B + MSE_B + 2, 256, 0, stream>>>(args);
  syrk_k<<<16, 256, 0, stream>>>(args);
  quad_k<<<128, 256, 0, stream>>>(args);
  final_k<<<1, 256, 0, stream>>>(args);
}

// Round 7
// 133.274 us; speedup vs baseline: 2.7360x; 1.0458x over previous
//
#include <hip/hip_runtime.h>
#include <hip/hip_bf16.h>
#include <math.h>

typedef unsigned short u16;
typedef float  f32x4  __attribute__((ext_vector_type(4)));
typedef __bf16 bf16x8 __attribute__((ext_vector_type(8)));

#define NPOS   4000
#define LDP    136       // padded bf16 row stride
#define TILE_CH 2176     // 128*136*2/16 16-byte chunks per 128-row tile
#define MSE_N  4194304
#define GATHER_B 256
#define MSE_B    512
#define TLD    132       // f32 voxel-tile row stride (pad, keeps 16B align)

__device__ __forceinline__ void load_lds16(const void* g, void* l) {
  __builtin_amdgcn_global_load_lds(
      (const __attribute__((address_space(1))) unsigned int*)g,
      (__attribute__((address_space(3))) unsigned int*)l, 16, 0, 0);
}

__device__ __forceinline__ float bf2f(u16 h) {
  unsigned u = ((unsigned)h) << 16;
  return __builtin_bit_cast(float, u);
}

struct Args {
  const float* Zs; const int* pos; const int* neg;
  const float4* fd; const float4* idf;
  u16* Pc; u16* Prow; float* G; float* S;
  float* qpos; float* qneg; float* sdpos; float* sdneg;
  float* msepart; float* out;
};

// ===== kernel 1: coalesced inverted gather + MSE partials + pad/G/S zero =====
__global__ __launch_bounds__(256) void prep_k(Args a) {
  __shared__ __align__(16) float tile[128 * TLD];   // 67,584 B
  __shared__ int mlist[1024];
  __shared__ int mcnt;
  int blk = blockIdx.x, tid = threadIdx.x;
  int wave = tid >> 6, lane = tid & 63;
  if (blk < GATHER_B) {
    int v0 = blk << 7;
    if (tid == 0) mcnt = 0;
    __syncthreads();
    // stage Zs[:, v0:v0+128] coalesced (float4)
    {
      int rq = tid >> 5;              // 0..7
      int c4 = (tid & 31) << 2;       // 0,4,...,124
      #pragma unroll
      for (int p = 0; p < 16; ++p) {
        int f = p * 8 + rq;
        float4 v = *(const float4*)(a.Zs + ((size_t)f << 15) + v0 + c4);
        *(float4*)&tile[f * TLD + c4] = v;
      }
    }
    // scan indices, build match list (col<<7 | local voxel)
    for (int k = 0; k < 4000; k += 256) {
      int i = k + tid;
      if (i < 4000) {
        unsigned dp = (unsigned)(a.pos[i] - v0);
        if (dp < 128u) { int m = atomicAdd(&mcnt, 1); mlist[m] = (i << 7) | dp; }
        unsigned dn = (unsigned)(a.neg[i] - v0);
        if (dn < 128u) { int m = atomicAdd(&mcnt, 1); mlist[m] = ((4096 + i) << 7) | dn; }
      }
    }
    __syncthreads();
    int nm = mcnt;
    for (int m = wave; m < nm; m += 4) {
      int e = mlist[m];
      int col = e >> 7, lv = e & 127;
      float x0 = tile[lane * TLD + lv];
      float x1 = tile[(lane + 64) * TLD + lv];
      float s = x0 * x0 + x1 * x1;
      #pragma unroll
      for (int o = 1; o < 64; o <<= 1) s += __shfl_xor(s, o, 64);
      float inv = 1.0f / fmaxf(sqrtf(s), 1e-12f);
      __hip_bfloat16 h0 = __float2bfloat16(x0 * inv);
      __hip_bfloat16 h1 = __float2bfloat16(x1 * inv);
      u16 b0 = *(u16*)&h0, b1 = *(u16*)&h1;
      a.Prow[(size_t)col * LDP + lane]      = b0;
      a.Prow[(size_t)col * LDP + lane + 64] = b1;
      size_t cbase = (size_t)(col >> 7) * (128 * LDP) + (col & 127);
      a.Pc[cbase + (size_t)lane * LDP]        = b0;
      a.Pc[cbase + (size_t)(lane + 64) * LDP] = b1;
    }
  } else if (blk < GATHER_B + MSE_B) {
    int b = blk - GATHER_B;
    float ms = 0.f;
    for (int idx = b * 256 + tid; idx < MSE_N / 4; idx += MSE_B * 256) {
      float4 u = a.fd[idx], w = a.idf[idx];
      float dx = u.x - w.x, dy = u.y - w.y, dz = u.z - w.z, dv = u.w - w.w;
      ms += dx * dx + dy * dy + dz * dz + dv * dv;
    }
    #pragma unroll
    for (int o = 1; o < 64; o <<= 1) ms += __shfl_xor(ms, o, 64);
    __shared__ float red[4];
    if (lane == 0) red[wave] = ms;
    __syncthreads();
    if (tid == 0) a.msepart[b] = red[0] + red[1] + red[2] + red[3];
  } else if (blk < GATHER_B + MSE_B + 2) {
    // zero invalid Pc sample columns (chunk 31 & 63, cols 32..127)
    int ch = (blk == GATHER_B + MSE_B) ? 31 : 63;
    for (int e = tid; e < 128 * 96; e += 256) {
      int f = e / 96, c = 32 + e % 96;
      a.Pc[(size_t)ch * (128 * LDP) + (size_t)f * LDP + c] = 0;
    }
  } else {
    // zero G (32768 f) + S (256 f) = 8256 float4, contiguous from a.G
    int b = blk - (GATHER_B + MSE_B + 2);
    float4 z = {0.f, 0.f, 0.f, 0.f};
    for (int i = b * 256 + tid; i < 8256; i += 512) ((float4*)a.G)[i] = z;
  }
}

// ===== kernel 2: SYRK -> atomic G[2][128][128] f32, + S column-sum atomics =====
__global__ __launch_bounds__(256) void syrk_k(Args a) {
  __shared__ __align__(16) u16 T0[128 * LDP];
  int blk = blockIdx.x, tid = threadIdx.x;     // 16 blocks: b<8 pos, b>=8 neg
  int wave = tid >> 6, lane = tid & 63;
  int wm = (wave >> 1) << 6, wn = (wave & 1) << 6;
  int r = lane & 15, q = lane >> 4;
  int sf = tid >> 1, sh = tid & 1;
  float ssum = 0.f;
  f32x4 acc[4][4];
  #pragma unroll
  for (int x = 0; x < 4; ++x)
    #pragma unroll
    for (int y = 0; y < 4; ++y) {
      acc[x][y][0] = 0.f; acc[x][y][1] = 0.f; acc[x][y][2] = 0.f; acc[x][y][3] = 0.f;
    }
  for (int it = 0; it < 4; ++it) {
    const u16* g = a.Pc + (size_t)(blk * 4 + it) * (128 * LDP);
    #pragma unroll
    for (int k = 0; k < 9; ++k) {
      int cc = k * 256 + tid;
      if (cc < TILE_CH) load_lds16(g + cc * 8, &T0[cc * 8]);
    }
    __syncthreads();
    #pragma unroll
    for (int kk = 0; kk < 4; ++kk) {
      int k0 = kk * 32 + q * 8;
      bf16x8 af[4], bfr[4];
      #pragma unroll
      for (int t = 0; t < 4; ++t) {
        af[t]  = *(const bf16x8*)&T0[(wm + t * 16 + r) * LDP + k0];
        bfr[t] = *(const bf16x8*)&T0[(wn + t * 16 + r) * LDP + k0];
      }
      #pragma unroll
      for (int mt = 0; mt < 4; ++mt)
        #pragma unroll
        for (int nt = 0; nt < 4; ++nt)
          acc[mt][nt] = __builtin_amdgcn_mfma_f32_16x16x32_bf16(
              af[mt], bfr[nt], acc[mt][nt], 0, 0, 0);
    }
    {
      const u16* base = &T0[sf * LDP + sh * 64];
      #pragma unroll
      for (int vb = 0; vb < 8; ++vb) {
        bf16x8 v = *(const bf16x8*)&base[vb * 8];
        #pragma unroll
        for (int j = 0; j < 8; ++j) ssum += (float)v[j];
      }
    }
    __syncthreads();
  }
  float* Gf = a.G + (size_t)(blk >> 3) * 16384;
  #pragma unroll
  for (int mt = 0; mt < 4; ++mt)
    #pragma unroll
    for (int nt = 0; nt < 4; ++nt)
      #pragma unroll
      for (int reg = 0; reg < 4; ++reg) {
        int ar = wm + mt * 16 + q * 4 + reg;
        int bc = wn + nt * 16 + r;
        atomicAdd(&Gf[ar * 128 + bc], acc[mt][nt][reg]);
      }
  ssum += __shfl_xor(ssum, 1, 64);
  if (sh == 0) atomicAdd(&a.S[(blk >> 3) * 128 + sf], ssum);
}

// ===== kernel 3: quadratic forms q_set[i] = p_i^T G_set p_i + S-dots =====
__global__ __launch_bounds__(256) void quad_k(Args a) {
  __shared__ __align__(16) u16 T0[128 * LDP];   // G in bf16
  __shared__ __align__(16) u16 T1[128 * LDP];   // P tile
  __shared__ float Sl[256];
  __shared__ float qld[2][128];
  int cb = blockIdx.x & 63, set = blockIdx.x >> 6, tid = threadIdx.x;
  Sl[tid] = a.S[tid];
  const u16* gP = a.Prow + (size_t)cb * (128 * LDP);
  #pragma unroll
  for (int k = 0; k < 9; ++k) {
    int cc = k * 256 + tid;
    if (cc < TILE_CH) load_lds16(gP + cc * 8, &T1[cc * 8]);
  }
  {
    int f = tid >> 1, half = (tid & 1) * 64;
    const float4* gsrc = (const float4*)(a.G + (size_t)set * 16384 + f * 128 + half);
    #pragma unroll
    for (int j16 = 0; j16 < 16; ++j16) {
      float4 v = gsrc[j16];
      __hip_bfloat16 c0 = __float2bfloat16(v.x), c1 = __float2bfloat16(v.y);
      __hip_bfloat16 c2 = __float2bfloat16(v.z), c3 = __float2bfloat16(v.w);
      ushort4 pk = { *(u16*)&c0, *(u16*)&c1, *(u16*)&c2, *(u16*)&c3 };
      *(ushort4*)&T0[f * LDP + half + j16 * 4] = pk;
    }
  }
  __syncthreads();
  int wave = tid >> 6, lane = tid & 63;
  int wm = (wave >> 1) << 6, wn = (wave & 1) << 6;
  int r = lane & 15, q = lane >> 4;
  f32x4 acc[4][4];
  #pragma unroll
  for (int x = 0; x < 4; ++x)
    #pragma unroll
    for (int y = 0; y < 4; ++y) {
      acc[x][y][0] = 0.f; acc[x][y][1] = 0.f; acc[x][y][2] = 0.f; acc[x][y][3] = 0.f;
    }
  #pragma unroll
  for (int kk = 0; kk < 4; ++kk) {
    int k0 = kk * 32 + q * 8;
    bf16x8 af[4], bfr[4];
    #pragma unroll
    for (int t = 0; t < 4; ++t) {
      af[t]  = *(const bf16x8*)&T0[(wm + t * 16 + r) * LDP + k0];
      bfr[t] = *(const bf16x8*)&T1[(wn + t * 16 + r) * LDP + k0];
    }
    #pragma unroll
    for (int mt = 0; mt < 4; ++mt)
      #pragma unroll
      for (int nt = 0; nt < 4; ++nt)
        acc[mt][nt] = __builtin_amdgcn_mfma_f32_16x16x32_bf16(
            af[mt], bfr[nt], acc[mt][nt], 0, 0, 0);
  }
  float qv[4] = {0.f, 0.f, 0.f, 0.f};
  #pragma unroll
  for (int nt = 0; nt < 4; ++nt) {
    int il = wn + nt * 16 + r;
    #pragma unroll
    for (int mt = 0; mt < 4; ++mt) {
      const u16* pp = &T1[il * LDP + wm + mt * 16 + q * 4];
      #pragma unroll
      for (int reg = 0; reg < 4; ++reg)
        qv[nt] += acc[mt][nt][reg] * bf2f(pp[reg]);
    }
  }
  #pragma unroll
  for (int nt = 0; nt < 4; ++nt) {
    qv[nt] += __shfl_xor(qv[nt], 16, 64);
    qv[nt] += __shfl_xor(qv[nt], 32, 64);
  }
  int half = wm >> 6;
  if (q == 0) {
    #pragma unroll
    for (int nt = 0; nt < 4; ++nt) qld[half][wn + nt * 16 + r] = qv[nt];
  }
  __syncthreads();
  float* qarr = set ? a.qneg : a.qpos;
  if (tid < 128) qarr[cb * 128 + tid] = qld[0][tid] + qld[1][tid];
  if (set == 0) {
    int which = tid >> 7, sl = tid & 127;
    const float* Sv = &Sl[which * 128];
    float d = 0.f;
    #pragma unroll
    for (int fb = 0; fb < 16; ++fb) {
      const u16* pv = &T1[sl * LDP + fb * 8];
      #pragma unroll
      for (int j = 0; j < 8; ++j) d += Sv[fb * 8 + j] * bf2f(pv[j]);
    }
    (which ? a.sdneg : a.sdpos)[cb * 128 + sl] = d;
  }
}

// ===== kernel 4: per-sample terms + MSE reduce + final combine =====
__global__ __launch_bounds__(256) void final_k(Args a) {
  int tid = threadIdx.x;
  int wave = tid >> 6, lane = tid & 63;
  float lg = 0.f, sm = 0.f;
  for (int col = tid; col < 8192; col += 256) {
    bool isp = col < NPOS;
    bool isn = (col >= 4096) && (col < 4096 + NPOS);
    if (isp || isn) {
      float qp = a.qpos[col], qn = a.qneg[col];
      float c = 1.0f / sqrtf(qp + qn);
      float qo  = isp ? qn : qp;
      float sdo = isp ? a.sdneg[col] : a.sdpos[col];
      float sds = isp ? a.sdpos[col] : a.sdneg[col];
      float denom = 4000.0f + c * sdo + 0.5f * c * c * qo;
      lg += logf(denom);
      sm += c * (sds - 1.0f);
    }
  }
  float ms = a.msepart[tid] + a.msepart[tid + 256];
  #pragma unroll
  for (int o = 1; o < 64; o <<= 1) {
    lg += __shfl_xor(lg, o, 64);
    sm += __shfl_xor(sm, o, 64);
    ms += __shfl_xor(ms, o, 64);
  }
  __shared__ float redf[12];
  if (lane == 0) { redf[wave] = lg; redf[4 + wave] = sm; redf[8 + wave] = ms; }
  __syncthreads();
  if (tid == 0) {
    float lgs = redf[0] + redf[1] + redf[2] + redf[3];
    float sms = redf[4] + redf[5] + redf[6] + redf[7];
    float mss = redf[8] + redf[9] + redf[10] + redf[11];
    a.out[0] = lgs - sms * (1.0f / 8000.0f) + 0.5f * (mss * (1.0f / (float)MSE_N));
  }
}

extern "C" void kernel_launch(void* const* d_in, const int* in_sizes, int n_in,
                              void* d_out, int out_size, void* d_ws, size_t ws_size,
                              hipStream_t stream) {
  char* ws = (char*)d_ws;
  Args args;
  args.Zs  = (const float*)d_in[0];
  args.pos = (const int*)d_in[1];
  args.neg = (const int*)d_in[2];
  args.fd  = (const float4*)d_in[3];
  args.idf = (const float4*)d_in[4];
  args.out = (float*)d_out;

  args.Pc      = (u16*)(ws + 0);            // 2,228,224 B
  args.Prow    = (u16*)(ws + 2228224);      // 2,228,224 -> 4,456,448
  args.G       = (float*)(ws + 4456448);    //   131,072 -> 4,587,520 (zeroed in prep)
  args.S       = (float*)(ws + 4587520);    //     1,024 -> 4,588,544 (zeroed in prep)
  args.qpos    = (float*)(ws + 4588544);    //    32,768 -> 4,621,312
  args.qneg    = (float*)(ws + 4621312);    //    32,768 -> 4,654,080
  args.sdpos   = (float*)(ws + 4654080);    //    32,768 -> 4,686,848
  args.sdneg   = (float*)(ws + 4686848);    //    32,768 -> 4,719,616
  args.msepart = (float*)(ws + 4719616);    //     2,048 -> 4,721,664

  prep_k<<<GATHER_B + MSE_B + 4, 256, 0, stream>>>(args);
  syrk_k<<<16, 256, 0, stream>>>(args);
  quad_k<<<128, 256, 0, stream>>>(args);
  final_k<<<1, 256, 0, stream>>>(args);
}